// Round 9
// baseline (82.826 us; speedup 1.0000x reference)
//
#include <hip/hip_runtime.h>
#include <math.h>

// Chamfer loss, B=32, N=2048, 3 used components.
// R9 = R8 (80.1 us champion) with atomic-free, init-free epilogues:
//  - main loop BYTE-IDENTICAL to R8 (seeded-x2, 5 VALU/pair, 256x256 tile,
//    thread = 16x16, grid (8,8,32) = 2048 blocks).
//  - row/col minima written as EXACT-SINGLE-WRITER partials (no atomicMin,
//    no ws sentinel memset, no init): ws_row[b][bi][bj][256] 2 MiB,
//    ws_col[b][bj][bi][256] 2 MiB, both coalesced via LDS funnels.
//  - sum kernel: min over 8 partials each side, sqrt, sum, 256 atomicAdds.
//  - out=0 folded into tile kernel. TOTAL: 2 dispatches, zero memsets.

#define NPTS   2048
#define NBATCH 32
#define NCH    8                       // 256-chunks per axis
#define WS_SIDE_FLOATS ((size_t)NBATCH * NCH * NCH * 256)   // 524288 = 2 MiB
#define EPSF   1e-16f
#define BIGF   3.4e38f

__device__ __forceinline__ float min3f(float a, float b, float c) {
    return fminf(fminf(a, b), c);    // -> v_min3_f32
}

__global__ __launch_bounds__(256) void chamfer_tile_kernel(
    const float* __restrict__ P, const float* __restrict__ Q,
    float* __restrict__ ws, float* __restrict__ out)
{
    __shared__ float4 sp[256];        // {x, y, z, |p|^2}
    __shared__ float4 sq[256];        // {-2x, -2y, -2z, |q|^2}
    __shared__ float  scol[4][256];   // per-wave col partials
    __shared__ float  rrow[256];      // row-min funnel (coalesced write-out)

    const int tid = threadIdx.x;
    const int tx  = tid & 15;         // col group
    const int ty  = tid >> 4;         // row group (0..15, spans 4 waves)
    const int bi  = blockIdx.x;       // row chunk (p)
    const int bj  = blockIdx.y;       // col chunk (q)
    const int b   = blockIdx.z;       // batch

    // init output accumulator (sum kernel runs strictly after this kernel)
    if (bi == 0 && bj == 0 && b == 0 && tid == 0) *out = 0.f;

    // ---- stage tile points (1 float4 load each, coalesced)
    {
        float4 pv = ((const float4*)P)[(size_t)b * NPTS + bi * 256 + tid];
        sp[tid] = make_float4(pv.y, pv.z, pv.w,
                              pv.y*pv.y + pv.z*pv.z + pv.w*pv.w);
        float4 qv = ((const float4*)Q)[(size_t)b * NPTS + bj * 256 + tid];
        sq[tid] = make_float4(-2.f*qv.y, -2.f*qv.z, -2.f*qv.w,
                              qv.y*qv.y + qv.z*qv.z + qv.w*qv.w);
    }
    __syncthreads();

    // ---- thread's 16 p rows: r = ty + 16k (broadcast reads, conflict-free)
    float px[16], py[16], pz[16], x2[16];
    #pragma unroll
    for (int k = 0; k < 16; ++k) {
        float4 v = sp[ty + 16 * k];
        px[k] = v.x; py[k] = v.y; pz[k] = v.z; x2[k] = v.w;
    }

    float rowacc[16], colacc[16];
    #pragma unroll
    for (int k = 0; k < 16; ++k) { rowacc[k] = BIGF; colacc[k] = BIGF; }

    // ---- main loop (identical to R8): t = dot' + x2 (x2 seeded innermost).
    // row: min over m of (t + y2) == full d2.  col: min over n of t.
    for (int jp = 0; jp < 8; ++jp) {
        float4 q0 = sq[tx + 32 * jp];        // j0 = 2*jp
        float4 q1 = sq[tx + 32 * jp + 16];   // j1 = 2*jp+1
        float c0 = BIGF, c1 = BIGF;
        #pragma unroll
        for (int k = 0; k < 16; k += 2) {
            float t00 = fmaf(px[k],   q0.x, fmaf(py[k],   q0.y, fmaf(pz[k],   q0.z, x2[k])));
            float t01 = fmaf(px[k],   q1.x, fmaf(py[k],   q1.y, fmaf(pz[k],   q1.z, x2[k])));
            float t10 = fmaf(px[k+1], q0.x, fmaf(py[k+1], q0.y, fmaf(pz[k+1], q0.z, x2[k+1])));
            float t11 = fmaf(px[k+1], q1.x, fmaf(py[k+1], q1.y, fmaf(pz[k+1], q1.z, x2[k+1])));
            rowacc[k]   = min3f(rowacc[k],   t00 + q0.w, t01 + q1.w);
            rowacc[k+1] = min3f(rowacc[k+1], t10 + q0.w, t11 + q1.w);
            c0 = min3f(c0, t00, t10);
            c1 = min3f(c1, t01, t11);
        }
        colacc[2*jp]     = c0;
        colacc[2*jp + 1] = c1;
    }

    // ---- row epilogue: reduce across tx (lane bits 0..3) -> rrow funnel
    #pragma unroll
    for (int k = 0; k < 16; ++k) {
        float v = rowacc[k];
        v = fminf(v, __shfl_xor(v, 1));
        v = fminf(v, __shfl_xor(v, 2));
        v = fminf(v, __shfl_xor(v, 4));
        v = fminf(v, __shfl_xor(v, 8));
        if (tx == 0) rrow[ty + 16 * k] = v;   // full d2 already
    }

    // ---- col epilogue: reduce across ty. In-wave: lane bits 4,5.
    #pragma unroll
    for (int j = 0; j < 16; ++j) {
        float v = colacc[j];
        v = fminf(v, __shfl_xor(v, 16));
        v = fminf(v, __shfl_xor(v, 32));
        colacc[j] = v;
    }
    {
        const int wv   = tid >> 6;
        const int lane = tid & 63;
        if (lane < 16) {               // lane == tx, w_ty == 0
            #pragma unroll
            for (int j = 0; j < 16; ++j) scol[wv][j * 16 + lane] = colacc[j];
        }
    }
    __syncthreads();

    // ---- coalesced exact-single-writer partial stores (no atomics)
    {
        float v = fminf(fminf(scol[0][tid], scol[1][tid]),
                        fminf(scol[2][tid], scol[3][tid]));
        float* wsC = ws + WS_SIDE_FLOATS;
        wsC[(((size_t)b * NCH + bj) * NCH + bi) * 256 + tid] = v + sq[tid].w;
        ws[(((size_t)b * NCH + bi) * NCH + bj) * 256 + tid] = rrow[tid];
    }
}

__global__ __launch_bounds__(256) void chamfer_sum_kernel(
    const float* __restrict__ ws, float* __restrict__ out)
{
    __shared__ float rbuf[4];
    const int tid = threadIdx.x;
    const int i   = blockIdx.x * 256 + tid;   // 0..65535
    const int b   = i >> 11;
    const int e   = i & 2047;
    const int ch  = e >> 8;                    // chunk index 0..7
    const int el  = e & 255;                   // element in chunk

    // row side: min over 8 bj partials (coalesced in el)
    float s;
    {
        const float* rb = ws + ((size_t)(b * NCH + ch) * NCH) * 256 + el;
        float v = BIGF;
        #pragma unroll
        for (int j = 0; j < NCH; ++j) v = fminf(v, rb[j * 256]);
        s = sqrtf(fmaxf(v, 0.f) + EPSF);
    }
    // col side: min over 8 bi partials (coalesced in el)
    {
        const float* cb = ws + WS_SIDE_FLOATS
                        + ((size_t)(b * NCH + ch) * NCH) * 256 + el;
        float v = BIGF;
        #pragma unroll
        for (int j = 0; j < NCH; ++j) v = fminf(v, cb[j * 256]);
        s += sqrtf(fmaxf(v, 0.f) + EPSF);
    }

    #pragma unroll
    for (int off = 32; off > 0; off >>= 1) s += __shfl_down(s, off);
    if ((tid & 63) == 0) rbuf[tid >> 6] = s;
    __syncthreads();
    if (tid == 0)
        atomicAdd(out, 0.5f * ((rbuf[0] + rbuf[1]) + (rbuf[2] + rbuf[3])));
}

extern "C" void kernel_launch(void* const* d_in, const int* in_sizes, int n_in,
                              void* d_out, int out_size, void* d_ws, size_t ws_size,
                              hipStream_t stream) {
    const float* P = (const float*)d_in[0];   // p[0] = first 32*2048*4 floats
    const float* Q = (const float*)d_in[1];
    float* out = (float*)d_out;
    float* ws  = (float*)d_ws;                // uses 4 MiB

    dim3 grid(NCH, NCH, NBATCH);              // 8 x 8 x 32 = 2048 blocks
    chamfer_tile_kernel<<<grid, 256, 0, stream>>>(P, Q, ws, out);
    chamfer_sum_kernel<<<256, 256, 0, stream>>>(ws, out);
}

// Round 11
// 79.079 us; speedup vs baseline: 1.0474x; 1.0474x over previous
//
#include <hip/hip_runtime.h>
#include <math.h>

// Chamfer loss, B=32, N=2048, 3 used components.
// R10 (resubmit; round 10 bench was a GPU-acquisition timeout, no data):
// MFMA main loop. d2[n][m] = x2[n]+y2[m] - 2 p.q computed by
// v_mfma_f32_32x32x16_bf16 with bf16-SPLIT operands (error ~2e-5, no fp16
// risk): g = -2q; A slots = [ph.x,ph.y,ph.z, pl.x,pl.y,pl.z, ph.x,ph.y]
// (lanes<32) / [ph.z,0..] (lanes>=32); B = [gh.x,gh.y,gh.z, gh.x,gh.y,gh.z,
// gl.x,gl.y] / [gl.z,0..]. Slot-paired products give ph*gh + pl*gh + ph*gl
// for all 3 comps, k-permutation-robust (A,B share the (half,slot)->k map).
// C seeded with x2[row]+y2[col] -> MFMA output IS d2. C/D layout (verified
// m74/m101): col=lane&31, row=(reg&3)+8*(reg>>2)+4*(lane>>5).
// Block = 128 rows x 1024 cols, grid (16,2,32)=1024 blocks, 4/CU; wave =
// 32 rows, sweeps 32 col-tiles: per tile ~43 VALU + 1 MFMA per 1024 pairs
// (vs 5 VALU/pair scalar). Col mins via LDS atomicMin (uint-cast, clamped);
// row mins in-register -> shfl reduce. Single-writer global partials
// (no init, no global atomics): ws_row[b][bi][jh][128] 512KB,
// ws_col[b][jh][bi][1024] 4MB. Sum kernel merges, sqrt, 0.5*sum.

#define NPTS   2048
#define NBATCH 32
#define NBI    16                      // 128-row chunks
#define NJH    2                       // 1024-col halves
#define WS_ROW_FLOATS ((size_t)NBATCH * NBI * NJH * 128)   // 131072 floats
#define EPSF   1e-16f
#define BIGF   3.4e38f

typedef __attribute__((ext_vector_type(8)))  short bf16x8;
typedef __attribute__((ext_vector_type(16))) float f32x16;
typedef __attribute__((ext_vector_type(4)))  unsigned int u32x4;

__device__ __forceinline__ float min3f(float a, float b, float c) {
    return fminf(fminf(a, b), c);      // -> v_min3_f32
}
__device__ __forceinline__ unsigned short bf16_rne(float f) {
    unsigned int u = __float_as_uint(f);
    return (unsigned short)((u + 0x7FFFu + ((u >> 16) & 1u)) >> 16);
}
__device__ __forceinline__ float bf16_f32(unsigned short h) {
    return __uint_as_float(((unsigned int)h) << 16);
}

__global__ __launch_bounds__(256, 4) void chamfer_mfma_kernel(
    const float* __restrict__ P, const float* __restrict__ Q,
    float* __restrict__ ws, float* __restrict__ out)
{
    __shared__ u32x4        sqlo[1024];   // B-frag, lanes<32 (16KB)
    __shared__ unsigned int sqhi[1024];   // B-frag slot0, lanes>=32 (4KB)
    __shared__ float        sy2[1024];    // |q3|^2 f32 (4KB)
    __shared__ float        sx2[128];     // |p3|^2 f32 (512B)
    __shared__ unsigned int scol[1024];   // col-min, uint-cast clamped (4KB)
    __shared__ float        srow[128];    // row-min funnel (512B)

    const int tid  = threadIdx.x;
    const int lane = tid & 63;
    const int wv   = tid >> 6;
    const int l31  = lane & 31;
    const int hi   = lane >> 5;        // k-half select
    const int bi   = blockIdx.x;       // 128-row chunk
    const int jh   = blockIdx.y;       // 1024-col half
    const int b    = blockIdx.z;       // batch

    if (bi == 0 && jh == 0 && b == 0 && tid == 0) *out = 0.f;

    // ---- stage q half: 4 cols/thread -> split bf16 frags + y2 + col init
    {
        const float4* Qb = (const float4*)Q + (size_t)b * NPTS + jh * 1024;
        #pragma unroll
        for (int s = 0; s < 4; ++s) {
            int c = tid + 256 * s;
            float4 qv = Qb[c];
            float gx = -2.f * qv.y, gy = -2.f * qv.z, gz = -2.f * qv.w;
            unsigned short hx = bf16_rne(gx), hy = bf16_rne(gy), hz = bf16_rne(gz);
            unsigned short lx = bf16_rne(gx - bf16_f32(hx));
            unsigned short ly = bf16_rne(gy - bf16_f32(hy));
            unsigned short lz = bf16_rne(gz - bf16_f32(hz));
            // slots s0..s7 = [hx,hy,hz, hx,hy,hz, lx,ly]
            sqlo[c] = (u32x4){ (unsigned)hx | ((unsigned)hy << 16),
                               (unsigned)hz | ((unsigned)hx << 16),
                               (unsigned)hy | ((unsigned)hz << 16),
                               (unsigned)lx | ((unsigned)ly << 16) };
            sqhi[c] = (unsigned)lz;               // slot0 = lz, rest 0
            sy2[c]  = qv.y*qv.y + qv.z*qv.z + qv.w*qv.w;
            scol[c] = 0x7F7F7F7Fu;
        }
    }

    // ---- A-frag: my row (lanes l and l+32 share row, different k-half)
    bf16x8 afrag;
    {
        const int rowl = wv * 32 + l31;
        float4 pv = ((const float4*)P)[(size_t)b * NPTS + bi * 128 + rowl];
        float x = pv.y, y = pv.z, z = pv.w;
        unsigned short hx = bf16_rne(x), hy = bf16_rne(y), hz = bf16_rne(z);
        unsigned short lx = bf16_rne(x - bf16_f32(hx));
        unsigned short ly = bf16_rne(y - bf16_f32(hy));
        unsigned short lz = bf16_rne(z - bf16_f32(hz));
        sx2[rowl] = x*x + y*y + z*z;   // dup-write by both halves, same value
        u32x4 araw;
        if (hi == 0)   // slots [hx,hy,hz, lx,ly,lz, hx,hy]
            araw = (u32x4){ (unsigned)hx | ((unsigned)hy << 16),
                            (unsigned)hz | ((unsigned)lx << 16),
                            (unsigned)ly | ((unsigned)lz << 16),
                            (unsigned)hx | ((unsigned)hy << 16) };
        else           // slots [hz, 0,0,0,0,0,0,0]
            araw = (u32x4){ (unsigned)hz, 0u, 0u, 0u };
        afrag = __builtin_bit_cast(bf16x8, araw);
    }
    __syncthreads();

    // ---- x2 seeds for my 16 C-rows: r(reg) = (reg&3)+8*(reg>>2)+4*hi (+32wv)
    float x2s[16];
    {
        const float* xb = &sx2[wv * 32 + 4 * hi];
        float4 xa = *(const float4*)(xb);        // rows +0..3   -> regs 0-3
        float4 xbv = *(const float4*)(xb + 8);   // rows +8..11  -> regs 4-7
        float4 xc = *(const float4*)(xb + 16);   // rows +16..19 -> regs 8-11
        float4 xd = *(const float4*)(xb + 24);   // rows +24..27 -> regs 12-15
        x2s[0]=xa.x;  x2s[1]=xa.y;  x2s[2]=xa.z;  x2s[3]=xa.w;
        x2s[4]=xbv.x; x2s[5]=xbv.y; x2s[6]=xbv.z; x2s[7]=xbv.w;
        x2s[8]=xc.x;  x2s[9]=xc.y;  x2s[10]=xc.z; x2s[11]=xc.w;
        x2s[12]=xd.x; x2s[13]=xd.y; x2s[14]=xd.z; x2s[15]=xd.w;
    }

    float rowacc[16];
    #pragma unroll
    for (int r = 0; r < 16; ++r) rowacc[r] = BIGF;

    // ---- sweep 32 col-tiles of 32
    #pragma unroll 2
    for (int t = 0; t < 32; ++t) {
        const int c = t * 32 + l31;
        float y2c = sy2[c];
        u32x4 braw;
        if (hi == 0) braw = sqlo[c];
        else         braw = (u32x4){ sqhi[c], 0u, 0u, 0u };
        bf16x8 bfrag = __builtin_bit_cast(bf16x8, braw);

        f32x16 cin;
        #pragma unroll
        for (int r = 0; r < 16; ++r) cin[r] = x2s[r] + y2c;

        f32x16 d = __builtin_amdgcn_mfma_f32_32x32x16_bf16(afrag, bfrag, cin,
                                                           0, 0, 0);
        #pragma unroll
        for (int r = 0; r < 16; ++r) rowacc[r] = fminf(rowacc[r], d[r]);

        // col-min over my 16 rows, then merge halves, publish via LDS atomic
        float m0 = min3f(min3f(d[0], d[1], d[2]),
                         min3f(d[3], d[4], d[5]),
                         min3f(d[6], d[7], d[8]));
        float m1 = min3f(min3f(d[9], d[10], d[11]),
                         min3f(d[12], d[13], d[14]), d[15]);
        float m  = fminf(m0, m1);
        m = fminf(m, __shfl_xor(m, 32));
        if (hi == 0)
            atomicMin(&scol[c], __float_as_uint(fmaxf(m, 0.f)));
    }

    // ---- row epilogue: reduce across 32 lanes of each half
    #pragma unroll
    for (int r = 0; r < 16; ++r) {
        float v = rowacc[r];
        v = fminf(v, __shfl_xor(v, 1));
        v = fminf(v, __shfl_xor(v, 2));
        v = fminf(v, __shfl_xor(v, 4));
        v = fminf(v, __shfl_xor(v, 8));
        v = fminf(v, __shfl_xor(v, 16));
        rowacc[r] = v;
    }
    if (l31 == 0) {                    // lanes 0 and 32 of each wave
        #pragma unroll
        for (int r = 0; r < 16; ++r)
            srow[wv * 32 + 4 * hi + (r & 3) + 8 * (r >> 2)] = rowacc[r];
    }
    __syncthreads();

    // ---- single-writer global partials (coalesced)
    if (tid < 128)
        ws[(((size_t)b * NBI + bi) * NJH + jh) * 128 + tid] = srow[tid];
    {
        float* cbase = ws + WS_ROW_FLOATS
                     + (((size_t)b * NJH + jh) * NBI + bi) * 1024;
        #pragma unroll
        for (int s = 0; s < 4; ++s) {
            int c = tid + 256 * s;
            cbase[c] = __uint_as_float(scol[c]);   // full d2, clamped >= 0
        }
    }
}

__global__ __launch_bounds__(256) void chamfer_sum_kernel(
    const float* __restrict__ ws, float* __restrict__ out)
{
    __shared__ float rbuf[4];
    const int tid = threadIdx.x;
    const int i   = blockIdx.x * 256 + tid;   // 0..65535
    const int b   = i >> 11;
    const int e   = i & 2047;

    // row side: min over 2 jh partials
    float s;
    {
        const int bi = e >> 7, el = e & 127;
        const float* rb = ws + ((size_t)(b * NBI + bi) * NJH) * 128 + el;
        float v = fminf(rb[0], rb[128]);
        s = sqrtf(fmaxf(v, 0.f) + EPSF);
    }
    // col side: min over 16 bi partials (coalesced in el)
    {
        const int jh = e >> 10, el = e & 1023;
        const float* cb = ws + WS_ROW_FLOATS
                        + ((size_t)(b * NJH + jh) * NBI) * 1024 + el;
        float v = BIGF;
        #pragma unroll
        for (int j = 0; j < NBI; ++j) v = fminf(v, cb[(size_t)j * 1024]);
        s += sqrtf(fmaxf(v, 0.f) + EPSF);
    }

    #pragma unroll
    for (int off = 32; off > 0; off >>= 1) s += __shfl_down(s, off);
    if ((tid & 63) == 0) rbuf[tid >> 6] = s;
    __syncthreads();
    if (tid == 0)
        atomicAdd(out, 0.5f * ((rbuf[0] + rbuf[1]) + (rbuf[2] + rbuf[3])));
}

extern "C" void kernel_launch(void* const* d_in, const int* in_sizes, int n_in,
                              void* d_out, int out_size, void* d_ws, size_t ws_size,
                              hipStream_t stream) {
    const float* P = (const float*)d_in[0];   // p[0] = first 32*2048*4 floats
    const float* Q = (const float*)d_in[1];
    float* out = (float*)d_out;
    float* ws  = (float*)d_ws;                // uses 4.5 MiB

    dim3 grid(NBI, NJH, NBATCH);              // 16 x 2 x 32 = 1024 blocks
    chamfer_mfma_kernel<<<grid, 256, 0, stream>>>(P, Q, ws, out);
    chamfer_sum_kernel<<<256, 256, 0, stream>>>(ws, out);
}